// Round 1
// 197.974 us; speedup vs baseline: 1.0160x; 1.0160x over previous
//
#include <hip/hip_runtime.h>

// LSTM B=8192, T=168, P=16, H=24, gates [i,f,g,o].
// Round-10: fused-denominator activations (10 -> 7 trans per cell).
//  - r9 analysis: VALUBusy 43.6% == 20 trans/wave/step * 16cyc * 2 waves
//    / 1472-cyc step -> trans-pipe issue is the dominant busy component.
//  - Algebraic fusion (exact):
//      c' = f*c + i*tanh(b) = [c(1+Y)(1+Z) + (1+X)(Z-1)] * rcp((1+X)(1+Y)(1+Z))
//           X=e^-f_pre, Y=e^-i_pre, Z=e^{2 g_pre}      (3 exp + 1 rcp, was 3+3)
//      h  = sigma(o)*tanh(c') = (W-1) * rcp((1+V)(1+W))
//           V=e^-o_pre, W=e^{2c'}                      (2 exp + 1 rcp, was 2+2)
//    -> 7 trans/cell. W's exp arg clamped at 18 (tanh(18)==1 in f32) so the
//    fused form can't hit inf*0=NaN where the old 1-2*rcp(1+exp) saturated.
//  - Everything else identical to r9: 8-tile self-aligned MFMA permutation,
//    1 ds_write_b32 + 1 ds_read_b128 h-exchange, ONE __syncthreads/step,
//    x-side MFMA pipelined one step ahead.

#define T_STEPS 168
#define P_FEAT  16
#define H_SZ    24
#define TCH     84    // t-chunk length (2 chunks)
#define NB      16    // batches per block

typedef _Float16 half8 __attribute__((ext_vector_type(8)));
typedef _Float16 h2    __attribute__((ext_vector_type(2)));
typedef float    f32x4 __attribute__((ext_vector_type(4)));

__device__ __forceinline__ float rcp_fast(float x) {
#if __has_builtin(__builtin_amdgcn_rcpf)
    return __builtin_amdgcn_rcpf(x);
#else
    return 1.0f / x;
#endif
}
__device__ __forceinline__ float exp2_fast(float x) {
#if __has_builtin(__builtin_amdgcn_exp2f)
    return __builtin_amdgcn_exp2f(x);
#else
    return exp2f(x);
#endif
}
__device__ __forceinline__ float tanh_f(float x) {
    return 1.0f - 2.0f * rcp_fast(1.0f + exp2_fast(x * 2.88539008f));
}
__device__ __forceinline__ h2 pack2(float a, float b) {
    h2 r; r.x = (_Float16)a; r.y = (_Float16)b; return r;
}

__global__ __launch_bounds__(256, 2) void lstm_4w(
    const float* __restrict__ x,
    const float* __restrict__ W_ih,
    const float* __restrict__ W_hh,
    const float* __restrict__ b_ih,
    const float* __restrict__ b_hh,
    const float* __restrict__ W_lin,
    const float* __restrict__ b_lin,
    float* __restrict__ out)
{
    __shared__ __align__(16) _Float16 xs16[NB][TCH][16];  // 43008 B (W-stage reused)
    __shared__ __align__(16) h2       hx[2][4][NB][4];    //  2048 B ping-pong h state
    __shared__ __align__(16) h2       zblk[8];            //    32 B zeros (B2 pad)
    __shared__ __align__(16) float    thbuf[NB][24];      //  1536 B epilogue

    const int tid  = threadIdx.x;
    const int w    = tid >> 6;       // wave 0..3: tiles {2w, 2w+1}
    const int lane = tid & 63;
    const int n    = lane & 15;      // batch col (B/C) == row p supplied (A)
    const int q    = lane >> 4;      // k-chunk (A/B) == output quad (C)

    // ---- one-time: stage fused W (f32) into xs16 space ----
    float* wstage = reinterpret_cast<float*>(&xs16[0][0][0]);  // 96*40 f32
    for (int idx = tid; idx < 96 * 40; idx += 256) {
        const int j = idx / 40;
        const int k = idx - j * 40;
        wstage[idx] = (k < 24) ? W_hh[j * 24 + k] : W_ih[j * 16 + (k - 24)];
    }
    __syncthreads();

    // ---- A-fragments for this wave's 2 tiles (mt = 2w+s) ----
    // row p (= lane&15): gate p%4 of unit 8*(p/4)+mt; rows p>=12 are zero.
    // A-frag layout [m120]: A[m=lane&15][k=quad*8+j].
    half8 A1[2], A2[2];
    f32x4 biasf[2];
    #pragma unroll
    for (int s = 0; s < 2; s++) {
        const int mt = 2 * w + s;
        const int p  = n;
        const bool vrow = (p < 12);
        const int grow = vrow ? ((p & 3) * 24 + 8 * (p >> 2) + mt) : 0;
        #pragma unroll
        for (int j = 0; j < 8; j++) {
            const int k = q * 8 + j;
            A1[s][j] = (vrow && k < 24) ? (_Float16)wstage[grow * 40 + k]      : (_Float16)0.0f;
            A2[s][j] = (vrow && k < 16) ? (_Float16)wstage[grow * 40 + 24 + k] : (_Float16)0.0f;
        }
        #pragma unroll
        for (int r = 0; r < 4; r++) {
            // lane (q,n) receives gates r of unit u = 8q+mt (valid for q<3)
            const int u = 8 * q + mt;
            biasf[s][r] = (q < 3) ? (b_ih[r * 24 + u] + b_hh[r * 24 + u]) : 0.0f;
        }
    }
    __syncthreads();   // wstage dead; x staging reuses the space

    // ---- zero hx (both buffers, incl. q=3 rows: stay 0 forever) + zblk ----
    {
        unsigned* hz = reinterpret_cast<unsigned*>(&hx[0][0][0][0]);   // 512 dwords
        for (int i = tid; i < 512; i += 256) hz[i] = 0u;
        if (tid < 8) reinterpret_cast<unsigned*>(zblk)[tid] = 0u;
    }
    __syncthreads();

    float c[2] = {0.0f, 0.0f};
    float hv[2] = {0.0f, 0.0f};

    const float4* xsrc = reinterpret_cast<const float4*>(x)
                       + (size_t)(blockIdx.x * NB) * (T_STEPS * P_FEAT / 4);

    // B2 source: quads 0..1 read x halves, quads 2..3 the zero block
    const _Float16* xrowbase = (q < 2) ? &xs16[n][0][q * 8]
                                       : reinterpret_cast<const _Float16*>(zblk);
    const int xstep = (q < 2) ? 16 : 0;

    int bufp = 0;
    for (int ch = 0; ch < 2; ch++) {
        // stage NB x TCH x 16 f32 -> f16: 5376 float4, 21 per thread
        for (int i = 0; i < 21; i++) {
            const int m   = tid + 256 * i;      // 0..5375
            const int b   = m / 336;            // 336 float4 per batch-chunk
            const int rem = m - b * 336;
            const float4 v = xsrc[(size_t)b * 672 + ch * 336 + rem];
            h2* dst = reinterpret_cast<h2*>(&xs16[0][0][0]) + b * 672 + rem * 2;
            dst[0] = pack2(v.x, v.y);
            dst[1] = pack2(v.z, v.w);
        }
        __syncthreads();

        // gx prologue for t=0 of this chunk
        f32x4 gx[2];
        {
            const half8 B2 = *reinterpret_cast<const half8*>(xrowbase);
            #pragma unroll
            for (int s = 0; s < 2; s++)
                gx[s] = __builtin_amdgcn_mfma_f32_16x16x32_f16(A2[s], B2, biasf[s], 0, 0, 0);
        }

        for (int t = 0; t < TCH; t++) {
            // B1: dword i = units (8q+2i, 8q+2i+1) = wave i's pair for (q,n)
            const half8 B1 = *reinterpret_cast<const half8*>(&hx[bufp][q][n][0]);
            // prefetch next step's x fragment (last iter: dummy index 0)
            const int tn = (t + 1 < TCH) ? t + 1 : 0;
            const half8 B2n = *reinterpret_cast<const half8*>(xrowbase + tn * xstep);

            f32x4 g[2];
            #pragma unroll
            for (int s = 0; s < 2; s++)
                g[s] = __builtin_amdgcn_mfma_f32_16x16x32_f16(A1[s], B1, gx[s], 0, 0, 0);
            #pragma unroll
            for (int s = 0; s < 2; s++)
                gx[s] = __builtin_amdgcn_mfma_f32_16x16x32_f16(A2[s], B2n, biasf[s], 0, 0, 0);

            // nonlinearities, fused-denominator form: 7 trans per unit
            //   c' = [c(1+Y)(1+Z) + (1+X)(Z-1)] * rcp((1+X)(1+Y)(1+Z))
            //   h  = (W-1) * rcp((1+V)(1+W)),  W = e^{2*min(c',18)}
            #pragma unroll
            for (int s = 0; s < 2; s++) {
                const float Y  = exp2_fast(g[s][0] * -1.44269504f);  // i-gate
                const float X  = exp2_fast(g[s][1] * -1.44269504f);  // f-gate
                const float Z  = exp2_fast(g[s][2] *  2.88539008f);  // g-gate
                const float V  = exp2_fast(g[s][3] * -1.44269504f);  // o-gate
                const float ax = 1.0f + X;
                const float ay = 1.0f + Y;
                const float az = 1.0f + Z;
                const float num = c[s] * ay * az + ax * (Z - 1.0f);
                const float cn  = num * rcp_fast(ax * ay * az);
                c[s] = cn;
                const float W  = exp2_fast(fminf(cn, 18.0f) * 2.88539008f);
                hv[s] = (W - 1.0f) * rcp_fast((1.0f + V) * (1.0f + W));
            }

            // publish own pair to the other buffer; q=3 has nothing to write
            if (q < 3) hx[1 - bufp][q][n][w] = pack2(hv[0], hv[1]);
            bufp ^= 1;
            __syncthreads();
        }
    }

    // ---- epilogue: out[b][u] = b_lin[u] + sum_k tanh(h[k]) * W_lin[u][k] ----
    if (q < 3) {
        thbuf[n][8 * q + 2 * w + 0] = tanh_f(hv[0]);
        thbuf[n][8 * q + 2 * w + 1] = tanh_f(hv[1]);
    }
    __syncthreads();

    if (q < 3) {
        const int batch = blockIdx.x * NB + n;
        #pragma unroll
        for (int s = 0; s < 2; s++) {
            const int u = 8 * q + 2 * w + s;
            const float* wl = &W_lin[u * 24];
            float acc = b_lin[u];
            #pragma unroll
            for (int k = 0; k < 24; k++) acc = fmaf(thbuf[n][k], wl[k], acc);
            out[(size_t)batch * 24 + u] = acc;
        }
    }
}

extern "C" void kernel_launch(void* const* d_in, const int* in_sizes, int n_in,
                              void* d_out, int out_size, void* d_ws, size_t ws_size,
                              hipStream_t stream) {
    const float* x     = (const float*)d_in[0];
    const float* W_ih  = (const float*)d_in[1];
    const float* W_hh  = (const float*)d_in[2];
    const float* b_ih  = (const float*)d_in[3];
    const float* b_hh  = (const float*)d_in[4];
    const float* W_lin = (const float*)d_in[5];
    const float* b_lin = (const float*)d_in[6];
    float* out = (float*)d_out;

    const int B = in_sizes[0] / (T_STEPS * P_FEAT);   // 8192
    dim3 grid(B / NB), block(256);                    // 512 blocks x 4 waves
    lstm_4w<<<grid, block, 0, stream>>>(x, W_ih, W_hh, b_ih, b_hh, W_lin, b_lin, out);
}